// Round 2
// baseline (206.030 us; speedup 1.0000x reference)
//
#include <hip/hip_runtime.h>

#define HIST_BINS 64
#define NBATCH 128
#define THREADS 256
#define BLOCKS_PER_BATCH 8   // 32768 elems/block <= 65535: u16 tree-sum can't overflow
#define WORDS 32             // 64 bins packed 2-per-u32 (u16 fields)

// ---------------------------------------------------------------------------
// Kernel 1: per-batch 64-bin histogram, ATOMIC-FREE.
// Per-THREAD private histograms in LDS, u16-packed 2 bins/word, laid out
// lh[word][tid] so each lane always hits bank tid%32 (2-way = free).
// Row 32 is a trash row for out-of-range values (branch-free cndmask).
// Merge: packed-u16 tree reduction across the 256 thread-columns.
// ---------------------------------------------------------------------------
__global__ __launch_bounds__(THREADS) void hist_kernel(
    const float* __restrict__ g, unsigned int* __restrict__ hist, int n_per_batch) {
    __shared__ unsigned int lh[WORDS + 1][THREADS];   // +1 = trash row, 33 KB

    const int tid = threadIdx.x;

    // zero private histograms (33*256 words / 256 threads = 33 each)
#pragma unroll
    for (int w = 0; w < WORDS + 1; ++w) lh[w][tid] = 0u;
    __syncthreads();

    const int batch = blockIdx.y;
    const int elems_per_block = n_per_batch / BLOCKS_PER_BATCH;   // 32768
    const float4* gp = (const float4*)(g + (size_t)batch * n_per_batch
                                         + (size_t)blockIdx.x * elems_per_block);
    const int n4 = elems_per_block >> 2;                          // 8192 float4s
    const float scale = 64.0f / 255.0f;

#pragma unroll 4
    for (int i = tid; i < n4; i += THREADS) {
        float4 v = gp[i];
        float vs[4] = {v.x, v.y, v.z, v.w};
#pragma unroll
        for (int j = 0; j < 4; ++j) {
            float val = vs[j];
            int bin = (int)floorf(val * scale);
            bin = min(max(bin, 0), HIST_BINS - 1);
            bool valid = (val >= 0.0f) && (val <= 255.0f);
            int w = valid ? (bin >> 1) : WORDS;        // invalid -> trash row
            lh[w][tid] += 1u << ((bin & 1) << 4);      // packed u16 increment
        }
    }
    __syncthreads();

    // tree-reduce the 256 thread-columns (packed u16: max 32768 < 65536, exact)
    for (int s = THREADS / 2; s >= 1; s >>= 1) {
        if (tid < s) {
#pragma unroll
            for (int w = 0; w < WORDS; ++w) lh[w][tid] += lh[w][tid + s];
        }
        __syncthreads();
    }

    if (tid < HIST_BINS) {
        unsigned int v = lh[tid >> 1][0];
        unsigned int c = (v >> ((tid & 1) << 4)) & 0xFFFFu;
        atomicAdd(&hist[batch * HIST_BINS + tid], c);   // 8 blocks/batch contend: cheap
    }
}

// ---------------------------------------------------------------------------
// Kernel 2: normalize histogram (L1) + MLP: relu(hist @ W1^T + b1) @ W2^T + b2
// One block (128 threads) per batch.
// ---------------------------------------------------------------------------
__global__ __launch_bounds__(128) void mlp_kernel(
    const unsigned int* __restrict__ hist,
    const float* __restrict__ W1, const float* __restrict__ b1,
    const float* __restrict__ W2, const float* __restrict__ b2,
    float* __restrict__ out) {
    __shared__ float hn[HIST_BINS];
    __shared__ float h[32];

    const int b   = blockIdx.x;
    const int tid = threadIdx.x;

    if (tid < HIST_BINS) hn[tid] = (float)hist[b * HIST_BINS + tid];
    __syncthreads();

    // L1 sum: counts are integers <= 2^18, exact in fp32 regardless of order
    float sum = 0.0f;
    for (int i = 0; i < HIST_BINS; ++i) sum += hn[i];
    const float denom = fmaxf(sum, 1e-12f);
    __syncthreads();

    if (tid < HIST_BINS) hn[tid] = hn[tid] / denom;  // divide (match ref rounding)
    __syncthreads();

    if (tid < 32) {
        float acc = b1[tid];
        for (int k = 0; k < HIST_BINS; ++k) acc += hn[k] * W1[tid * HIST_BINS + k];
        h[tid] = fmaxf(acc, 0.0f);
    }
    __syncthreads();

    float acc = b2[tid];
    for (int k = 0; k < 32; ++k) acc += h[k] * W2[tid * 32 + k];
    out[b * 128 + tid] = acc;
}

extern "C" void kernel_launch(void* const* d_in, const int* in_sizes, int n_in,
                              void* d_out, int out_size, void* d_ws, size_t ws_size,
                              hipStream_t stream) {
    const float* g  = (const float*)d_in[0];
    const float* W1 = (const float*)d_in[1];
    const float* b1 = (const float*)d_in[2];
    const float* W2 = (const float*)d_in[3];
    const float* b2 = (const float*)d_in[4];
    float* out = (float*)d_out;

    unsigned int* hist = (unsigned int*)d_ws;
    const int n_per_batch = in_sizes[0] / NBATCH;   // 512*512 = 262144

    // d_ws is poisoned to 0xAA before every timed launch — zero it (capture-safe)
    hipMemsetAsync(hist, 0, NBATCH * HIST_BINS * sizeof(unsigned int), stream);

    hist_kernel<<<dim3(BLOCKS_PER_BATCH, NBATCH), THREADS, 0, stream>>>(g, hist, n_per_batch);
    mlp_kernel<<<NBATCH, 128, 0, stream>>>(hist, W1, b1, W2, b2, out);
}

// Round 3
// 203.370 us; speedup vs baseline: 1.0131x; 1.0131x over previous
//
#include <hip/hip_runtime.h>

#define HIST_BINS 64
#define NBATCH 128
#define THREADS 256
#define BLOCKS_PER_BATCH 8   // 32768 elems/block <= 65535: u16 tree-sum can't overflow
#define WORDS 32             // 64 bins packed 2-per-u32 (u16 fields)

// ---------------------------------------------------------------------------
// Kernel 1: per-batch 64-bin histogram, ATOMIC-FREE, MEMSET-FREE.
// Per-THREAD private histograms in LDS, u16-packed 2 bins/word, laid out
// lh[word][tid] so each lane always hits bank tid%32 (2-way = free, m136).
// Row 32 is a trash row for out-of-range values (branch-free select).
// Merge: packed-u16 tree reduction across the 256 thread-columns, then each
// block writes its 64-bin PARTIAL to ws (full overwrite -> poison-safe).
// ---------------------------------------------------------------------------
__global__ __launch_bounds__(THREADS) void hist_kernel(
    const float* __restrict__ g, unsigned int* __restrict__ partial, int n_per_batch) {
    __shared__ unsigned int lh[WORDS + 1][THREADS];   // +1 = trash row, 33 KB

    const int tid = threadIdx.x;

#pragma unroll
    for (int w = 0; w < WORDS + 1; ++w) lh[w][tid] = 0u;
    __syncthreads();

    const int batch = blockIdx.y;
    const int elems_per_block = n_per_batch / BLOCKS_PER_BATCH;   // 32768
    const float4* gp = (const float4*)(g + (size_t)batch * n_per_batch
                                         + (size_t)blockIdx.x * elems_per_block);
    const int n4 = elems_per_block >> 2;                          // 8192 float4s
    const float scale = 64.0f / 255.0f;

#pragma unroll 4
    for (int i = tid; i < n4; i += THREADS) {
        float4 v = gp[i];
        float vs[4] = {v.x, v.y, v.z, v.w};
#pragma unroll
        for (int j = 0; j < 4; ++j) {
            float val = vs[j];
            int bin = (int)floorf(val * scale);
            bin = min(max(bin, 0), HIST_BINS - 1);
            bool valid = (val >= 0.0f) && (val <= 255.0f);
            int w = valid ? (bin >> 1) : WORDS;        // invalid -> trash row
            lh[w][tid] += 1u << ((bin & 1) << 4);      // packed u16 increment
        }
    }
    __syncthreads();

    // tree-reduce the 256 thread-columns (packed u16: max 32768 < 65536, exact)
    for (int s = THREADS / 2; s >= 1; s >>= 1) {
        if (tid < s) {
#pragma unroll
            for (int w = 0; w < WORDS; ++w) lh[w][tid] += lh[w][tid + s];
        }
        __syncthreads();
    }

    // non-atomic partial write: partial[(batch*BPB + blk)*64 + bin]
    if (tid < HIST_BINS) {
        unsigned int v = lh[tid >> 1][0];
        unsigned int c = (v >> ((tid & 1) << 4)) & 0xFFFFu;
        partial[((size_t)batch * BLOCKS_PER_BATCH + blockIdx.x) * HIST_BINS + tid] = c;
    }
}

// ---------------------------------------------------------------------------
// Kernel 2: reduce partials + L1 normalize + MLP:
//   relu(hist @ W1^T + b1) @ W2^T + b2.   One block (128 threads) per batch.
// ---------------------------------------------------------------------------
__global__ __launch_bounds__(128) void mlp_kernel(
    const unsigned int* __restrict__ partial,
    const float* __restrict__ W1, const float* __restrict__ b1,
    const float* __restrict__ W2, const float* __restrict__ b2,
    float* __restrict__ out) {
    __shared__ float hn[HIST_BINS];
    __shared__ float h[32];

    const int b   = blockIdx.x;
    const int tid = threadIdx.x;

    if (tid < HIST_BINS) {
        unsigned int s = 0;
        const unsigned int* p = partial + (size_t)b * BLOCKS_PER_BATCH * HIST_BINS + tid;
#pragma unroll
        for (int k = 0; k < BLOCKS_PER_BATCH; ++k) s += p[k * HIST_BINS];
        hn[tid] = (float)s;       // integer counts <= 2^18: exact in fp32
    }
    __syncthreads();

    float sum = 0.0f;
    for (int i = 0; i < HIST_BINS; ++i) sum += hn[i];   // exact integer sum
    const float denom = fmaxf(sum, 1e-12f);
    __syncthreads();

    if (tid < HIST_BINS) hn[tid] = hn[tid] / denom;  // divide (match ref rounding)
    __syncthreads();

    if (tid < 32) {
        float acc = b1[tid];
        for (int k = 0; k < HIST_BINS; ++k) acc += hn[k] * W1[tid * HIST_BINS + k];
        h[tid] = fmaxf(acc, 0.0f);
    }
    __syncthreads();

    float acc = b2[tid];
    for (int k = 0; k < 32; ++k) acc += h[k] * W2[tid * 32 + k];
    out[b * 128 + tid] = acc;
}

extern "C" void kernel_launch(void* const* d_in, const int* in_sizes, int n_in,
                              void* d_out, int out_size, void* d_ws, size_t ws_size,
                              hipStream_t stream) {
    const float* g  = (const float*)d_in[0];
    const float* W1 = (const float*)d_in[1];
    const float* b1 = (const float*)d_in[2];
    const float* W2 = (const float*)d_in[3];
    const float* b2 = (const float*)d_in[4];
    float* out = (float*)d_out;

    unsigned int* partial = (unsigned int*)d_ws;    // 128*8*64*4 B = 256 KB, fully
    const int n_per_batch = in_sizes[0] / NBATCH;   // overwritten every call

    hist_kernel<<<dim3(BLOCKS_PER_BATCH, NBATCH), THREADS, 0, stream>>>(g, partial, n_per_batch);
    mlp_kernel<<<NBATCH, 128, 0, stream>>>(partial, W1, b1, W2, b2, out);
}